// Round 14
// baseline (102.282 us; speedup 1.0000x reference)
//
#include <hip/hip_runtime.h>
#include <hip/hip_fp16.h>
#include <type_traits>

// GCN 2-layer forward, 8 dispatches:
// [hist1+wsplit] -> scanexc(self-basing) -> part1 -> part2 ->
// GEMM1 -> agg1 -> GEMM2 -> agg2
// CSR built by two-stage bucket partition (no global atomics); hs buffers fp16
// prescaled by dinv. Aggregations: wave-uniform dst (scalar csr loads),
// 8/4/1 cascade fp16 gathers (r12-proven floor; 4/16/masked16/pair all lose).

#define NBC   128          // partition blocks (stage-1)
#define BSH   7            // bucket shift: 128 nodes / bucket
#define NBMAX 512          // max buckets supported (n <= 65536)
#define CAP   8192         // part2 LDS record capacity (mean 2046, 136 sigma)

typedef __bf16 bf16x8 __attribute__((ext_vector_type(8)));
typedef float  f32x4  __attribute__((ext_vector_type(4)));

__device__ __forceinline__ unsigned short f2bf(float f) {
    unsigned u = __float_as_uint(f);
    unsigned r = u + 0x7fff + ((u >> 16) & 1);   // round-nearest-even to bf16
    return (unsigned short)(r >> 16);
}
__device__ __forceinline__ float bf2f(unsigned short h) {
    return __uint_as_float(((unsigned)h) << 16);
}

__device__ __forceinline__ void wsplit_one(const float* __restrict__ W,
                                           unsigned short* __restrict__ out,
                                           int K, int idx) {
    int k = idx >> 6, c = idx & 63;
    float v = W[k * 64 + c];
    unsigned short hi = f2bf(v);
    unsigned short lo = f2bf(v - bf2f(hi));
    int T = K / 32;
    int t = k >> 5, kk = k & 31, g = kk >> 3, j = kk & 7;
    int ct = c >> 4, lane = g * 16 + (c & 15);
    out[(((size_t)(0 * T + t) * 4 + ct) * 64 + lane) * 8 + j] = hi;
    out[(((size_t)(1 * T + t) * 4 + ct) * 64 + lane) * 8 + j] = lo;
}

// blocks [0,NBC): histogram T[bucket][block]; blocks [NBC, NBC+48): W split
__global__ __launch_bounds__(256) void k_hist_wsplit(
    const int* __restrict__ dst, int* __restrict__ T, int E, int nbuck,
    const float* __restrict__ W1, const float* __restrict__ W2,
    unsigned short* __restrict__ W1s, unsigned short* __restrict__ W2s) {
    __shared__ int hist[NBMAX];
    if (blockIdx.x >= NBC) {
        int i = (blockIdx.x - NBC) * 256 + threadIdx.x;
        if (i < 128 * 64) wsplit_one(W1, W1s, 128, i);
        else if (i < 128 * 64 + 64 * 64) wsplit_one(W2, W2s, 64, i - 128 * 64);
        return;
    }
    for (int i = threadIdx.x; i < nbuck; i += 256) hist[i] = 0;
    __syncthreads();
    const int per = (((E + NBC - 1) / NBC) + 3) & ~3;
    const int beg = blockIdx.x * per, end = min(beg + per, E);
    for (int i = beg + threadIdx.x; i < end; i += 256)
        atomicAdd(&hist[dst[i] >> BSH], 1);
    __syncthreads();
    for (int b = threadIdx.x; b < nbuck; b += 256)
        T[b * NBC + blockIdx.x] = hist[b];
}

// exclusive scan, self-basing: each block cooperatively sums in[0..blk*1024)
// for its base (L2-hot, ~48 loads/thread max), then Hillis-Steele its chunk.
__global__ __launch_bounds__(1024) void k_scanexc2(
    const int* __restrict__ in, int* __restrict__ out, int m) {
    __shared__ int sh[1024];
    __shared__ int red[16];
    const int t = threadIdx.x;
    const int i = blockIdx.x * 1024 + t;
    const int pre = blockIdx.x * 1024;
    int ps = 0;
    for (int k = t; k < pre; k += 1024) ps += in[k];
#pragma unroll
    for (int o = 32; o; o >>= 1) ps += __shfl_down(ps, o);
    if ((t & 63) == 0) red[t >> 6] = ps;
    const int v = (i < m) ? in[i] : 0;
    sh[t] = v;
    __syncthreads();
    int base = 0;
#pragma unroll
    for (int w = 0; w < 16; ++w) base += red[w];
#pragma unroll
    for (int o = 1; o < 1024; o <<= 1) {
        int add = (t >= o) ? sh[t - o] : 0;
        __syncthreads();
        sh[t] += add;
        __syncthreads();
    }
    if (i < m) out[i] = base + sh[t] - v;
}

// stage-1 partition: block writes packed (d&127)<<17|src into its private
// contiguous run per bucket. Only LDS atomics. int4-vectorized edge reads.
__global__ __launch_bounds__(256) void k_part1(
    const int* __restrict__ src, const int* __restrict__ dst,
    const int* __restrict__ Toff, unsigned* __restrict__ stage, int E, int nbuck) {
    __shared__ int base[NBMAX];
    __shared__ int cnt[NBMAX];
    for (int i = threadIdx.x; i < nbuck; i += 256) {
        base[i] = Toff[i * NBC + blockIdx.x];
        cnt[i] = 0;
    }
    __syncthreads();
    const int per = (((E + NBC - 1) / NBC) + 3) & ~3;   // multiple of 4
    const int beg = blockIdx.x * per, end = min(beg + per, E);
    if (beg >= end) return;
    const int nquad = (end - beg) >> 2;
    for (int q = threadIdx.x; q < nquad; q += 256) {
        const int i = beg + q * 4;
        int4 s4 = *(const int4*)(src + i);
        int4 d4 = *(const int4*)(dst + i);
        int ss[4] = {s4.x, s4.y, s4.z, s4.w};
        int dd[4] = {d4.x, d4.y, d4.z, d4.w};
#pragma unroll
        for (int k = 0; k < 4; ++k) {
            int b = dd[k] >> BSH;
            int p = atomicAdd(&cnt[b], 1);
            stage[base[b] + p] = ((unsigned)(dd[k] & 127) << 17) | (unsigned)ss[k];
        }
    }
    const int tb = beg + nquad * 4;
    for (int i = tb + threadIdx.x; i < end; i += 256) {
        int d = dst[i], s = src[i];
        int b = d >> BSH;
        int p = atomicAdd(&cnt[b], 1);
        stage[base[b] + p] = ((unsigned)(d & 127) << 17) | (unsigned)s;
    }
}

// stage-2: one block per bucket; LDS-staged single-pass sort + coalesced
// writeback; emits rowptr + dinv. Global fallback if len > CAP.
__global__ __launch_bounds__(256) void k_part2(
    const int* __restrict__ Toff, const unsigned* __restrict__ stage,
    int* __restrict__ csr, int* __restrict__ rowptr, float* __restrict__ dinv,
    int n, int E, int nbuck) {
    __shared__ unsigned buf[CAP];
    __shared__ unsigned srt[CAP];
    __shared__ int cnt[128], sc[128], curs[128];
    __shared__ int rbs, res;
    const int t = threadIdx.x;
    const int b = blockIdx.x;
    if (t < 128) cnt[t] = 0;
    if (t == 0) {
        rbs = Toff[b * NBC];
        res = (b == nbuck - 1) ? E : Toff[(b + 1) * NBC];
    }
    __syncthreads();
    const int rb = rbs, re = res, len = re - rb;
    if (len <= CAP) {
        for (int i = t; i < len; i += 256) {
            unsigned r = stage[rb + i];
            buf[i] = r;
            atomicAdd(&cnt[(r >> 17) & 127], 1);
        }
        __syncthreads();
        if (t < 128) sc[t] = cnt[t];
        __syncthreads();
#pragma unroll
        for (int o = 1; o < 128; o <<= 1) {
            int add = (t < 128 && t >= o) ? sc[t - o] : 0;
            __syncthreads();
            if (t < 128) sc[t] += add;
            __syncthreads();
        }
        if (t < 128) {
            curs[t] = sc[t] - cnt[t];
            const int gi = b * 128 + t;
            if (gi < n) {
                rowptr[gi] = rb + sc[t] - cnt[t];
                dinv[gi] = rsqrtf((float)cnt[t] + 1.f);   // +1 = self-loop
                if (gi == n - 1) rowptr[n] = rb + sc[t];  // == E
            }
        }
        __syncthreads();
        for (int i = t; i < len; i += 256) {
            unsigned r = buf[i];
            int p = atomicAdd(&curs[(r >> 17) & 127], 1);
            srt[p] = r & 0x1FFFF;
        }
        __syncthreads();
        for (int i = t; i < len; i += 256) csr[rb + i] = (int)srt[i];
    } else {
        for (int i = rb + t; i < re; i += 256)
            atomicAdd(&cnt[(stage[i] >> 17) & 127], 1);
        __syncthreads();
        if (t < 128) sc[t] = cnt[t];
        __syncthreads();
#pragma unroll
        for (int o = 1; o < 128; o <<= 1) {
            int add = (t < 128 && t >= o) ? sc[t - o] : 0;
            __syncthreads();
            if (t < 128) sc[t] += add;
            __syncthreads();
        }
        if (t < 128) {
            curs[t] = rb + sc[t] - cnt[t];
            const int gi = b * 128 + t;
            if (gi < n) {
                rowptr[gi] = rb + sc[t] - cnt[t];
                dinv[gi] = rsqrtf((float)cnt[t] + 1.f);
                if (gi == n - 1) rowptr[n] = rb + sc[t];
            }
        }
        __syncthreads();
        for (int i = rb + t; i < re; i += 256) {
            unsigned r = stage[i];
            int p = atomicAdd(&curs[(r >> 17) & 127], 1);
            csr[p] = (int)(r & 0x1FFFF);
        }
    }
}

// hs[n x 64] = half((A[n x K] @ W[K x 64]) * dinv[row]) via bf16-split MFMA.
// One wave per 16 rows, no LDS, no barriers. A dtype = float or half.
template<int K, bool LEAKY, typename AT>
__global__ __launch_bounds__(256) void k_gemm_mfma(
    const AT* __restrict__ A, const unsigned short* __restrict__ Ws,
    const float* __restrict__ dinv, __half* __restrict__ C, int n) {
    constexpr int T = K / 32;
    const int lane = threadIdx.x & 63;
    const int w = blockIdx.x * 4 + (threadIdx.x >> 6);
    const int r0 = w * 16;
    if (r0 >= n) return;
    const int g = lane >> 4, rA = lane & 15;

    bf16x8 ahi[T], alo[T];
    const AT* arow = A + (size_t)(r0 + rA) * K + g * 8;
#pragma unroll
    for (int t = 0; t < T; ++t) {
        float f[8];
        if constexpr (std::is_same<AT, float>::value) {
            float4 v0 = *(const float4*)(arow + t * 32);
            float4 v1 = *(const float4*)(arow + t * 32 + 4);
            f[0] = v0.x; f[1] = v0.y; f[2] = v0.z; f[3] = v0.w;
            f[4] = v1.x; f[5] = v1.y; f[6] = v1.z; f[7] = v1.w;
        } else {
            union { uint4 q; __half h[8]; } u;
            u.q = *(const uint4*)(arow + t * 32);
#pragma unroll
            for (int j = 0; j < 8; ++j) f[j] = __half2float(u.h[j]);
        }
        union { unsigned short u[8]; bf16x8 v; } H, L;
#pragma unroll
        for (int j = 0; j < 8; ++j) {
            float x = f[j];
            if (LEAKY) x = x > 0.f ? x : 0.01f * x;
            unsigned short h = f2bf(x);
            H.u[j] = h;
            L.u[j] = f2bf(x - bf2f(h));
        }
        ahi[t] = H.v; alo[t] = L.v;
    }

    f32x4 acc[4];
#pragma unroll
    for (int ct = 0; ct < 4; ++ct) acc[ct] = (f32x4){0.f, 0.f, 0.f, 0.f};
#pragma unroll
    for (int ct = 0; ct < 4; ++ct) {
#pragma unroll
        for (int t = 0; t < T; ++t) {
            union { uint4 q; bf16x8 v; } Bh, Bl;
            Bh.q = *(const uint4*)(Ws + (((size_t)(0 * T + t) * 4 + ct) * 64 + lane) * 8);
            Bl.q = *(const uint4*)(Ws + (((size_t)(1 * T + t) * 4 + ct) * 64 + lane) * 8);
            acc[ct] = __builtin_amdgcn_mfma_f32_16x16x32_bf16(ahi[t], Bh.v, acc[ct], 0, 0, 0);
            acc[ct] = __builtin_amdgcn_mfma_f32_16x16x32_bf16(ahi[t], Bl.v, acc[ct], 0, 0, 0);
            acc[ct] = __builtin_amdgcn_mfma_f32_16x16x32_bf16(alo[t], Bh.v, acc[ct], 0, 0, 0);
        }
    }

    float dv[4];
#pragma unroll
    for (int r = 0; r < 4; ++r) dv[r] = dinv[r0 + g * 4 + r];
    __half* crow = C + (size_t)(r0 + g * 4) * 64 + rA;
#pragma unroll
    for (int ct = 0; ct < 4; ++ct)
#pragma unroll
        for (int r = 0; r < 4; ++r)
            crow[(size_t)r * 64 + ct * 16] = __float2half_rn(acc[ct][r] * dv[r]);
}

// out[d] = (sum_e hs[s_e] + hs[d]) * dinv[d] + bias   (OT = half or float)
// One wave per dst row; d wave-uniform -> csr loads are scalar (SMEM);
// 8/4/1 cascade keeps 8 fp16 gathers (128B each) in flight (r12-proven).
template<typename OT>
__global__ __launch_bounds__(256) void k_aggcsr(
    const int* __restrict__ rowptr, const int* __restrict__ csr,
    const float* __restrict__ dinv, const __half* __restrict__ hs,
    const float* __restrict__ bias, OT* __restrict__ out, int n) {
    const int lane = threadIdx.x & 63;
    const int wid  = blockIdx.x * 4 + (threadIdx.x >> 6);
    const int nw   = gridDim.x * 4;
    const float bl = bias[lane];
    for (int dd = wid; dd < n; dd += nw) {
        const int d = __builtin_amdgcn_readfirstlane(dd);
        const int beg = rowptr[d], end = rowptr[d + 1];
        float a0 = 0.f, a1 = 0.f, a2 = 0.f, a3 = 0.f;
        float a4 = 0.f, a5 = 0.f, a6 = 0.f, a7 = 0.f;
        int j = beg;
        for (; j + 8 <= end; j += 8) {
            int s0 = csr[j + 0], s1 = csr[j + 1], s2 = csr[j + 2], s3 = csr[j + 3];
            int s4 = csr[j + 4], s5 = csr[j + 5], s6 = csr[j + 6], s7 = csr[j + 7];
            a0 += __half2float(hs[(size_t)s0 * 64 + lane]);
            a1 += __half2float(hs[(size_t)s1 * 64 + lane]);
            a2 += __half2float(hs[(size_t)s2 * 64 + lane]);
            a3 += __half2float(hs[(size_t)s3 * 64 + lane]);
            a4 += __half2float(hs[(size_t)s4 * 64 + lane]);
            a5 += __half2float(hs[(size_t)s5 * 64 + lane]);
            a6 += __half2float(hs[(size_t)s6 * 64 + lane]);
            a7 += __half2float(hs[(size_t)s7 * 64 + lane]);
        }
        for (; j + 4 <= end; j += 4) {
            int s0 = csr[j + 0], s1 = csr[j + 1], s2 = csr[j + 2], s3 = csr[j + 3];
            a0 += __half2float(hs[(size_t)s0 * 64 + lane]);
            a1 += __half2float(hs[(size_t)s1 * 64 + lane]);
            a2 += __half2float(hs[(size_t)s2 * 64 + lane]);
            a3 += __half2float(hs[(size_t)s3 * 64 + lane]);
        }
        for (; j < end; ++j)
            a0 += __half2float(hs[(size_t)csr[j] * 64 + lane]);
        const float di = dinv[d];
        const float acc = ((a0 + a1) + (a2 + a3)) + ((a4 + a5) + (a6 + a7));
        const float v = (acc + __half2float(hs[(size_t)d * 64 + lane])) * di + bl;
        if constexpr (std::is_same<OT, __half>::value)
            out[(size_t)d * 64 + lane] = __float2half_rn(v);
        else
            out[(size_t)d * 64 + lane] = v;
    }
}

extern "C" void kernel_launch(void* const* d_in, const int* in_sizes, int n_in,
                              void* d_out, int out_size, void* d_ws, size_t ws_size,
                              hipStream_t stream) {
    const float* x  = (const float*)d_in[0];
    const int*   ei = (const int*)d_in[1];
    const float* W1 = (const float*)d_in[2];
    const float* b1 = (const float*)d_in[3];
    const float* W2 = (const float*)d_in[4];
    const float* b2 = (const float*)d_in[5];
    float* out = (float*)d_out;

    const int n = in_sizes[0] / 128;   // 50000
    const int E = in_sizes[1] / 2;     // 800000
    const int* src = ei;
    const int* dst = ei + E;

    const int nbuck = (n + 127) >> BSH;        // 391
    const int m = nbuck * NBC;                 // 50048 table entries
    const int nb2 = (m + 1023) / 1024;         // 49 scan blocks

    char* ws = (char*)d_ws;
    size_t off = 0;
    auto alloc = [&](size_t bytes) { void* p = ws + off; off = (off + bytes + 255) & ~(size_t)255; return p; };
    int*      T      = (int*)alloc((size_t)m * 4);
    int*      Toff   = (int*)alloc((size_t)m * 4);
    unsigned* stage  = (unsigned*)alloc((size_t)E * 4);
    int*      csr    = (int*)alloc((size_t)E * 4);
    int*      rowptr = (int*)alloc((size_t)(n + 1) * 4);
    float*    dinv   = (float*)alloc((size_t)n * 4);
    __half*   hs     = (__half*)alloc((size_t)n * 64 * 2);
    __half*   out1   = (__half*)alloc((size_t)n * 64 * 2);
    unsigned short* W1s = (unsigned short*)alloc((size_t)2 * 128 * 64 * 2);
    unsigned short* W2s = (unsigned short*)alloc((size_t)2 * 64 * 64 * 2);
    (void)ws_size; (void)n_in; (void)out_size;

    const int wsplitBlocks = (128 * 64 + 64 * 64) / 256;   // 48

    k_hist_wsplit<<<NBC + wsplitBlocks, 256, 0, stream>>>(dst, T, E, nbuck, W1, W2, W1s, W2s);
    k_scanexc2<<<nb2, 1024, 0, stream>>>(T, Toff, m);
    k_part1   <<<NBC, 256, 0, stream>>>(src, dst, Toff, stage, E, nbuck);
    k_part2   <<<nbuck, 256, 0, stream>>>(Toff, stage, csr, rowptr, dinv, n, E, nbuck);

    const int gemmBlocks = ((n + 15) / 16 + 3) / 4;   // one wave per 16 rows
    k_gemm_mfma<128, false, float><<<gemmBlocks, 256, 0, stream>>>(x, W1s, dinv, hs, n);
    k_aggcsr<__half><<<2048, 256, 0, stream>>>(rowptr, csr, dinv, hs, b1, out1, n);

    k_gemm_mfma<64, true, __half><<<gemmBlocks, 256, 0, stream>>>(out1, W2s, dinv, hs, n);
    k_aggcsr<float><<<2048, 256, 0, stream>>>(rowptr, csr, dinv, hs, b2, out, n);
}

// Round 15
// 97.015 us; speedup vs baseline: 1.0543x; 1.0543x over previous
//
#include <hip/hip_runtime.h>
#include <hip/hip_fp16.h>
#include <type_traits>

// GCN 2-layer forward, 9 dispatches (r12 configuration — best measured):
// [hist1+wsplit] -> bsum -> scanexc(folded sbsum) -> part1 -> part2 ->
// GEMM1 -> agg1 -> GEMM2 -> agg2
// CSR built by two-stage bucket partition (no global atomics); hs buffers fp16
// prescaled by dinv. Aggregations: wave-uniform dst (scalar csr loads),
// 8/4/1 cascade fp16 gathers (proven floor; 4/16/masked16/pair all lose).

#define NBC   128          // partition blocks (stage-1)
#define BSH   7            // bucket shift: 128 nodes / bucket
#define NBMAX 512          // max buckets supported (n <= 65536)
#define CAP   8192         // part2 LDS record capacity (mean 2046, 136 sigma)

typedef __bf16 bf16x8 __attribute__((ext_vector_type(8)));
typedef float  f32x4  __attribute__((ext_vector_type(4)));

__device__ __forceinline__ unsigned short f2bf(float f) {
    unsigned u = __float_as_uint(f);
    unsigned r = u + 0x7fff + ((u >> 16) & 1);   // round-nearest-even to bf16
    return (unsigned short)(r >> 16);
}
__device__ __forceinline__ float bf2f(unsigned short h) {
    return __uint_as_float(((unsigned)h) << 16);
}

__device__ __forceinline__ void wsplit_one(const float* __restrict__ W,
                                           unsigned short* __restrict__ out,
                                           int K, int idx) {
    int k = idx >> 6, c = idx & 63;
    float v = W[k * 64 + c];
    unsigned short hi = f2bf(v);
    unsigned short lo = f2bf(v - bf2f(hi));
    int T = K / 32;
    int t = k >> 5, kk = k & 31, g = kk >> 3, j = kk & 7;
    int ct = c >> 4, lane = g * 16 + (c & 15);
    out[(((size_t)(0 * T + t) * 4 + ct) * 64 + lane) * 8 + j] = hi;
    out[(((size_t)(1 * T + t) * 4 + ct) * 64 + lane) * 8 + j] = lo;
}

// blocks [0,NBC): histogram T[bucket][block]; blocks [NBC, NBC+48): W split
__global__ __launch_bounds__(256) void k_hist_wsplit(
    const int* __restrict__ dst, int* __restrict__ T, int E, int nbuck,
    const float* __restrict__ W1, const float* __restrict__ W2,
    unsigned short* __restrict__ W1s, unsigned short* __restrict__ W2s) {
    __shared__ int hist[NBMAX];
    if (blockIdx.x >= NBC) {
        int i = (blockIdx.x - NBC) * 256 + threadIdx.x;
        if (i < 128 * 64) wsplit_one(W1, W1s, 128, i);
        else if (i < 128 * 64 + 64 * 64) wsplit_one(W2, W2s, 64, i - 128 * 64);
        return;
    }
    for (int i = threadIdx.x; i < nbuck; i += 256) hist[i] = 0;
    __syncthreads();
    const int per = (((E + NBC - 1) / NBC) + 3) & ~3;
    const int beg = blockIdx.x * per, end = min(beg + per, E);
    for (int i = beg + threadIdx.x; i < end; i += 256)
        atomicAdd(&hist[dst[i] >> BSH], 1);
    __syncthreads();
    for (int b = threadIdx.x; b < nbuck; b += 256)
        T[b * NBC + blockIdx.x] = hist[b];
}

// per-block (1024-elem) partial sums of T
__global__ __launch_bounds__(1024) void k_bsum(const int* __restrict__ in,
                                               int* __restrict__ bsum, int m) {
    __shared__ int red[16];
    const int t = threadIdx.x;
    const int i = blockIdx.x * 1024 + t;
    int v = (i < m) ? in[i] : 0;
#pragma unroll
    for (int o = 32; o; o >>= 1) v += __shfl_down(v, o);
    if ((t & 63) == 0) red[t >> 6] = v;
    __syncthreads();
    if (t == 0) {
        int s = 0;
#pragma unroll
        for (int w = 0; w < 16; ++w) s += red[w];
        bsum[blockIdx.x] = s;
    }
}

// exclusive scan with folded top-level: each block scans bsum[0..nb) in LDS
// (nb <= 64) to get its base, then Hillis-Steele over its 1024 chunk.
__global__ __launch_bounds__(1024) void k_scanexc2(
    const int* __restrict__ in, const int* __restrict__ bsum,
    int* __restrict__ out, int m, int nb) {
    __shared__ int sh[1024];
    __shared__ int bb[64];
    __shared__ int base;
    const int t = threadIdx.x;
    const int i = blockIdx.x * 1024 + t;
    if (t < 64) bb[t] = (t < nb) ? bsum[t] : 0;
    const int v = (i < m) ? in[i] : 0;
    sh[t] = v;
    __syncthreads();
    if (t == 0) {
        int run = 0;
        const int lim = blockIdx.x;
        for (int k = 0; k < lim; ++k) run += bb[k];
        base = run;
    }
#pragma unroll
    for (int o = 1; o < 1024; o <<= 1) {
        int add = (t >= o) ? sh[t - o] : 0;
        __syncthreads();
        sh[t] += add;
        __syncthreads();
    }
    if (i < m) out[i] = base + sh[t] - v;
}

// stage-1 partition: block writes packed (d&127)<<17|src into its private
// contiguous run per bucket. Only LDS atomics. int4-vectorized edge reads.
__global__ __launch_bounds__(256) void k_part1(
    const int* __restrict__ src, const int* __restrict__ dst,
    const int* __restrict__ Toff, unsigned* __restrict__ stage, int E, int nbuck) {
    __shared__ int base[NBMAX];
    __shared__ int cnt[NBMAX];
    for (int i = threadIdx.x; i < nbuck; i += 256) {
        base[i] = Toff[i * NBC + blockIdx.x];
        cnt[i] = 0;
    }
    __syncthreads();
    const int per = (((E + NBC - 1) / NBC) + 3) & ~3;   // multiple of 4
    const int beg = blockIdx.x * per, end = min(beg + per, E);
    if (beg >= end) return;
    const int nquad = (end - beg) >> 2;
    for (int q = threadIdx.x; q < nquad; q += 256) {
        const int i = beg + q * 4;
        int4 s4 = *(const int4*)(src + i);
        int4 d4 = *(const int4*)(dst + i);
        int ss[4] = {s4.x, s4.y, s4.z, s4.w};
        int dd[4] = {d4.x, d4.y, d4.z, d4.w};
#pragma unroll
        for (int k = 0; k < 4; ++k) {
            int b = dd[k] >> BSH;
            int p = atomicAdd(&cnt[b], 1);
            stage[base[b] + p] = ((unsigned)(dd[k] & 127) << 17) | (unsigned)ss[k];
        }
    }
    const int tb = beg + nquad * 4;
    for (int i = tb + threadIdx.x; i < end; i += 256) {
        int d = dst[i], s = src[i];
        int b = d >> BSH;
        int p = atomicAdd(&cnt[b], 1);
        stage[base[b] + p] = ((unsigned)(d & 127) << 17) | (unsigned)s;
    }
}

// stage-2: one block per bucket; LDS-staged single-pass sort + coalesced
// writeback; emits rowptr + dinv. Global fallback if len > CAP.
__global__ __launch_bounds__(256) void k_part2(
    const int* __restrict__ Toff, const unsigned* __restrict__ stage,
    int* __restrict__ csr, int* __restrict__ rowptr, float* __restrict__ dinv,
    int n, int E, int nbuck) {
    __shared__ unsigned buf[CAP];
    __shared__ unsigned srt[CAP];
    __shared__ int cnt[128], sc[128], curs[128];
    __shared__ int rbs, res;
    const int t = threadIdx.x;
    const int b = blockIdx.x;
    if (t < 128) cnt[t] = 0;
    if (t == 0) {
        rbs = Toff[b * NBC];
        res = (b == nbuck - 1) ? E : Toff[(b + 1) * NBC];
    }
    __syncthreads();
    const int rb = rbs, re = res, len = re - rb;
    if (len <= CAP) {
        for (int i = t; i < len; i += 256) {
            unsigned r = stage[rb + i];
            buf[i] = r;
            atomicAdd(&cnt[(r >> 17) & 127], 1);
        }
        __syncthreads();
        if (t < 128) sc[t] = cnt[t];
        __syncthreads();
#pragma unroll
        for (int o = 1; o < 128; o <<= 1) {
            int add = (t < 128 && t >= o) ? sc[t - o] : 0;
            __syncthreads();
            if (t < 128) sc[t] += add;
            __syncthreads();
        }
        if (t < 128) {
            curs[t] = sc[t] - cnt[t];
            const int gi = b * 128 + t;
            if (gi < n) {
                rowptr[gi] = rb + sc[t] - cnt[t];
                dinv[gi] = rsqrtf((float)cnt[t] + 1.f);   // +1 = self-loop
                if (gi == n - 1) rowptr[n] = rb + sc[t];  // == E
            }
        }
        __syncthreads();
        for (int i = t; i < len; i += 256) {
            unsigned r = buf[i];
            int p = atomicAdd(&curs[(r >> 17) & 127], 1);
            srt[p] = r & 0x1FFFF;
        }
        __syncthreads();
        for (int i = t; i < len; i += 256) csr[rb + i] = (int)srt[i];
    } else {
        for (int i = rb + t; i < re; i += 256)
            atomicAdd(&cnt[(stage[i] >> 17) & 127], 1);
        __syncthreads();
        if (t < 128) sc[t] = cnt[t];
        __syncthreads();
#pragma unroll
        for (int o = 1; o < 128; o <<= 1) {
            int add = (t < 128 && t >= o) ? sc[t - o] : 0;
            __syncthreads();
            if (t < 128) sc[t] += add;
            __syncthreads();
        }
        if (t < 128) {
            curs[t] = rb + sc[t] - cnt[t];
            const int gi = b * 128 + t;
            if (gi < n) {
                rowptr[gi] = rb + sc[t] - cnt[t];
                dinv[gi] = rsqrtf((float)cnt[t] + 1.f);
                if (gi == n - 1) rowptr[n] = rb + sc[t];
            }
        }
        __syncthreads();
        for (int i = rb + t; i < re; i += 256) {
            unsigned r = stage[i];
            int p = atomicAdd(&curs[(r >> 17) & 127], 1);
            csr[p] = (int)(r & 0x1FFFF);
        }
    }
}

// hs[n x 64] = half((A[n x K] @ W[K x 64]) * dinv[row]) via bf16-split MFMA.
// One wave per 16 rows, no LDS, no barriers. A dtype = float or half.
template<int K, bool LEAKY, typename AT>
__global__ __launch_bounds__(256) void k_gemm_mfma(
    const AT* __restrict__ A, const unsigned short* __restrict__ Ws,
    const float* __restrict__ dinv, __half* __restrict__ C, int n) {
    constexpr int T = K / 32;
    const int lane = threadIdx.x & 63;
    const int w = blockIdx.x * 4 + (threadIdx.x >> 6);
    const int r0 = w * 16;
    if (r0 >= n) return;
    const int g = lane >> 4, rA = lane & 15;

    bf16x8 ahi[T], alo[T];
    const AT* arow = A + (size_t)(r0 + rA) * K + g * 8;
#pragma unroll
    for (int t = 0; t < T; ++t) {
        float f[8];
        if constexpr (std::is_same<AT, float>::value) {
            float4 v0 = *(const float4*)(arow + t * 32);
            float4 v1 = *(const float4*)(arow + t * 32 + 4);
            f[0] = v0.x; f[1] = v0.y; f[2] = v0.z; f[3] = v0.w;
            f[4] = v1.x; f[5] = v1.y; f[6] = v1.z; f[7] = v1.w;
        } else {
            union { uint4 q; __half h[8]; } u;
            u.q = *(const uint4*)(arow + t * 32);
#pragma unroll
            for (int j = 0; j < 8; ++j) f[j] = __half2float(u.h[j]);
        }
        union { unsigned short u[8]; bf16x8 v; } H, L;
#pragma unroll
        for (int j = 0; j < 8; ++j) {
            float x = f[j];
            if (LEAKY) x = x > 0.f ? x : 0.01f * x;
            unsigned short h = f2bf(x);
            H.u[j] = h;
            L.u[j] = f2bf(x - bf2f(h));
        }
        ahi[t] = H.v; alo[t] = L.v;
    }

    f32x4 acc[4];
#pragma unroll
    for (int ct = 0; ct < 4; ++ct) acc[ct] = (f32x4){0.f, 0.f, 0.f, 0.f};
#pragma unroll
    for (int ct = 0; ct < 4; ++ct) {
#pragma unroll
        for (int t = 0; t < T; ++t) {
            union { uint4 q; bf16x8 v; } Bh, Bl;
            Bh.q = *(const uint4*)(Ws + (((size_t)(0 * T + t) * 4 + ct) * 64 + lane) * 8);
            Bl.q = *(const uint4*)(Ws + (((size_t)(1 * T + t) * 4 + ct) * 64 + lane) * 8);
            acc[ct] = __builtin_amdgcn_mfma_f32_16x16x32_bf16(ahi[t], Bh.v, acc[ct], 0, 0, 0);
            acc[ct] = __builtin_amdgcn_mfma_f32_16x16x32_bf16(ahi[t], Bl.v, acc[ct], 0, 0, 0);
            acc[ct] = __builtin_amdgcn_mfma_f32_16x16x32_bf16(alo[t], Bh.v, acc[ct], 0, 0, 0);
        }
    }

    float dv[4];
#pragma unroll
    for (int r = 0; r < 4; ++r) dv[r] = dinv[r0 + g * 4 + r];
    __half* crow = C + (size_t)(r0 + g * 4) * 64 + rA;
#pragma unroll
    for (int ct = 0; ct < 4; ++ct)
#pragma unroll
        for (int r = 0; r < 4; ++r)
            crow[(size_t)r * 64 + ct * 16] = __float2half_rn(acc[ct][r] * dv[r]);
}

// out[d] = (sum_e hs[s_e] + hs[d]) * dinv[d] + bias   (OT = half or float)
// One wave per dst row; d wave-uniform -> csr loads are scalar (SMEM);
// 8/4/1 cascade keeps 8 fp16 gathers (128B each) in flight (r12-proven).
template<typename OT>
__global__ __launch_bounds__(256) void k_aggcsr(
    const int* __restrict__ rowptr, const int* __restrict__ csr,
    const float* __restrict__ dinv, const __half* __restrict__ hs,
    const float* __restrict__ bias, OT* __restrict__ out, int n) {
    const int lane = threadIdx.x & 63;
    const int wid  = blockIdx.x * 4 + (threadIdx.x >> 6);
    const int nw   = gridDim.x * 4;
    const float bl = bias[lane];
    for (int dd = wid; dd < n; dd += nw) {
        const int d = __builtin_amdgcn_readfirstlane(dd);
        const int beg = rowptr[d], end = rowptr[d + 1];
        float a0 = 0.f, a1 = 0.f, a2 = 0.f, a3 = 0.f;
        float a4 = 0.f, a5 = 0.f, a6 = 0.f, a7 = 0.f;
        int j = beg;
        for (; j + 8 <= end; j += 8) {
            int s0 = csr[j + 0], s1 = csr[j + 1], s2 = csr[j + 2], s3 = csr[j + 3];
            int s4 = csr[j + 4], s5 = csr[j + 5], s6 = csr[j + 6], s7 = csr[j + 7];
            a0 += __half2float(hs[(size_t)s0 * 64 + lane]);
            a1 += __half2float(hs[(size_t)s1 * 64 + lane]);
            a2 += __half2float(hs[(size_t)s2 * 64 + lane]);
            a3 += __half2float(hs[(size_t)s3 * 64 + lane]);
            a4 += __half2float(hs[(size_t)s4 * 64 + lane]);
            a5 += __half2float(hs[(size_t)s5 * 64 + lane]);
            a6 += __half2float(hs[(size_t)s6 * 64 + lane]);
            a7 += __half2float(hs[(size_t)s7 * 64 + lane]);
        }
        for (; j + 4 <= end; j += 4) {
            int s0 = csr[j + 0], s1 = csr[j + 1], s2 = csr[j + 2], s3 = csr[j + 3];
            a0 += __half2float(hs[(size_t)s0 * 64 + lane]);
            a1 += __half2float(hs[(size_t)s1 * 64 + lane]);
            a2 += __half2float(hs[(size_t)s2 * 64 + lane]);
            a3 += __half2float(hs[(size_t)s3 * 64 + lane]);
        }
        for (; j < end; ++j)
            a0 += __half2float(hs[(size_t)csr[j] * 64 + lane]);
        const float di = dinv[d];
        const float acc = ((a0 + a1) + (a2 + a3)) + ((a4 + a5) + (a6 + a7));
        const float v = (acc + __half2float(hs[(size_t)d * 64 + lane])) * di + bl;
        if constexpr (std::is_same<OT, __half>::value)
            out[(size_t)d * 64 + lane] = __float2half_rn(v);
        else
            out[(size_t)d * 64 + lane] = v;
    }
}

extern "C" void kernel_launch(void* const* d_in, const int* in_sizes, int n_in,
                              void* d_out, int out_size, void* d_ws, size_t ws_size,
                              hipStream_t stream) {
    const float* x  = (const float*)d_in[0];
    const int*   ei = (const int*)d_in[1];
    const float* W1 = (const float*)d_in[2];
    const float* b1 = (const float*)d_in[3];
    const float* W2 = (const float*)d_in[4];
    const float* b2 = (const float*)d_in[5];
    float* out = (float*)d_out;

    const int n = in_sizes[0] / 128;   // 50000
    const int E = in_sizes[1] / 2;     // 800000
    const int* src = ei;
    const int* dst = ei + E;

    const int nbuck = (n + 127) >> BSH;        // 391
    const int m = nbuck * NBC;                 // 50048 table entries
    const int nb2 = (m + 1023) / 1024;         // 49 scan blocks

    char* ws = (char*)d_ws;
    size_t off = 0;
    auto alloc = [&](size_t bytes) { void* p = ws + off; off = (off + bytes + 255) & ~(size_t)255; return p; };
    int*      T      = (int*)alloc((size_t)m * 4);
    int*      Toff   = (int*)alloc((size_t)m * 4);
    int*      bsum   = (int*)alloc((size_t)nb2 * 4);
    unsigned* stage  = (unsigned*)alloc((size_t)E * 4);
    int*      csr    = (int*)alloc((size_t)E * 4);
    int*      rowptr = (int*)alloc((size_t)(n + 1) * 4);
    float*    dinv   = (float*)alloc((size_t)n * 4);
    __half*   hs     = (__half*)alloc((size_t)n * 64 * 2);
    __half*   out1   = (__half*)alloc((size_t)n * 64 * 2);
    unsigned short* W1s = (unsigned short*)alloc((size_t)2 * 128 * 64 * 2);
    unsigned short* W2s = (unsigned short*)alloc((size_t)2 * 64 * 64 * 2);
    (void)ws_size; (void)n_in; (void)out_size;

    const int wsplitBlocks = (128 * 64 + 64 * 64) / 256;   // 48

    k_hist_wsplit<<<NBC + wsplitBlocks, 256, 0, stream>>>(dst, T, E, nbuck, W1, W2, W1s, W2s);
    k_bsum    <<<nb2, 1024, 0, stream>>>(T, bsum, m);
    k_scanexc2<<<nb2, 1024, 0, stream>>>(T, bsum, Toff, m, nb2);
    k_part1   <<<NBC, 256, 0, stream>>>(src, dst, Toff, stage, E, nbuck);
    k_part2   <<<nbuck, 256, 0, stream>>>(Toff, stage, csr, rowptr, dinv, n, E, nbuck);

    const int gemmBlocks = ((n + 15) / 16 + 3) / 4;   // one wave per 16 rows
    k_gemm_mfma<128, false, float><<<gemmBlocks, 256, 0, stream>>>(x, W1s, dinv, hs, n);
    k_aggcsr<__half><<<2048, 256, 0, stream>>>(rowptr, csr, dinv, hs, b1, out1, n);

    k_gemm_mfma<64, true, __half><<<gemmBlocks, 256, 0, stream>>>(out1, W2s, dinv, hs, n);
    k_aggcsr<float><<<2048, 256, 0, stream>>>(rowptr, csr, dinv, hs, b2, out, n);
}